// Round 8
// baseline (268.822 us; speedup 1.0000x reference)
//
#include <hip/hip_runtime.h>
#include <hip/hip_fp16.h>

#define FEAT 32
#define BIN_NODES 128
#define BIN_SHIFT 7
#define SEG 2048          // edges per wave-segment
#define WPB 4             // wave-segments per block
#define SRC_BITS 20
#define SRC_MASK 0xFFFFF

// Block-local int64-vs-int32 detection: odd 32-bit words of an int64 index
// array (values < 2^31) are all zero; for int32 they are random node ids.
__device__ __forceinline__ int block_detect_int64(const int* __restrict__ raw32, int* nz) {
    if (threadIdx.x == 0) *nz = 0;
    __syncthreads();
    if (raw32[2 * threadIdx.x + 1] != 0) *nz = 1;
    __syncthreads();
    return (*nz == 0) ? 1 : 0;
}

__device__ __forceinline__ int load_idx(const void* raw, int f, long long i) {
    return f ? (int)((const long long*)raw)[i] : ((const int*)raw)[i];
}

// Phase A: per-(segment,bin) histogram, wave-private copies (no cross-wave
// contention). mat[s*nb + b], segment-major.
__global__ void binA_kernel(const void* __restrict__ raw, int* __restrict__ mat,
                            int e, int nb, int nseg) {
    extern __shared__ int hist[];  // WPB*nb + 1
    int t = threadIdx.x;
    for (int i = t; i < WPB * nb; i += 256) hist[i] = 0;
    int f = block_detect_int64((const int*)raw, &hist[WPB * nb]);  // syncs cover zeroing
    int w = t >> 6, lane = t & 63;
    int s = blockIdx.x * WPB + w;
    if (s < nseg) {
        int* hw = hist + w * nb;
        long long base = (long long)s * SEG;
        int cnt = (int)min((long long)SEG, (long long)e - base);
        for (int i = lane; i < cnt; i += 64) {
            int d = load_idx(raw, f, (long long)e + base + i);
            atomicAdd(&hw[d >> BIN_SHIFT], 1);
        }
    }
    __syncthreads();
    for (int w2 = 0; w2 < WPB; ++w2) {
        int s2 = blockIdx.x * WPB + w2;
        if (s2 >= nseg) break;
        for (int b = t; b < nb; b += 256) mat[(size_t)s2 * nb + b] = hist[w2 * nb + b];
    }
}

// logical L = b*nseg + s (bin-major) <-> physical p = s*nb + b
__device__ __forceinline__ size_t l2p(int L, int nb, int nseg) {
    int b = L / nseg;
    int s = L - b * nseg;
    return (size_t)s * nb + b;
}

__global__ void scan1_kernel(int* __restrict__ mat, int* __restrict__ bsum,
                             int M, int nb, int nseg) {
    __shared__ int sd[256];
    int t = threadIdx.x;
    int L = blockIdx.x * 256 + t;
    size_t p = 0; int v = 0;
    if (L < M) { p = l2p(L, nb, nseg); v = mat[p]; }
    sd[t] = v;
    __syncthreads();
    for (int off = 1; off < 256; off <<= 1) {
        int add = (t >= off) ? sd[t - off] : 0;
        __syncthreads();
        sd[t] += add;
        __syncthreads();
    }
    if (L < M) mat[p] = sd[t] - v;   // exclusive within scan-block
    if (t == 255) bsum[blockIdx.x] = sd[t];
}

// Generic single-block scan: K elements per thread (K<=4 by construction).
__global__ void scan2_kernel(int* __restrict__ bsum, int nbks) {
    __shared__ int sd[1024];
    int t = threadIdx.x;
    int K = (nbks + 1023) >> 10;
    if (K > 4) K = 4;
    int base = t * K;
    int loc[4] = {0, 0, 0, 0};
    int s = 0;
    for (int k = 0; k < K; ++k) {
        int v = (base + k < nbks) ? bsum[base + k] : 0;
        loc[k] = s; s += v;
    }
    sd[t] = s;
    __syncthreads();
    for (int off = 1; off < 1024; off <<= 1) {
        int add = (t >= off) ? sd[t - off] : 0;
        __syncthreads();
        sd[t] += add;
        __syncthreads();
    }
    int excl = sd[t] - s;
    for (int k = 0; k < K; ++k) if (base + k < nbks) bsum[base + k] = excl + loc[k];
}

// Phase C: scatter packed records grouped by bin. Wave-private cursors (exact
// per-segment bases from the scan) -> no cross-wave LDS contention, no global
// atomics. rec = src | dst_local<<20.
__global__ void binC_kernel(const void* __restrict__ raw, const int* __restrict__ mat,
                            const int* __restrict__ bsum, int* __restrict__ packed,
                            int e, int nb, int nseg) {
    extern __shared__ int cur[];  // WPB*nb + 1
    int t = threadIdx.x;
    int f = block_detect_int64((const int*)raw, &cur[WPB * nb]);
    for (int w2 = 0; w2 < WPB; ++w2) {
        int s2 = blockIdx.x * WPB + w2;
        for (int b = t; b < nb; b += 256)
            cur[w2 * nb + b] = (s2 < nseg)
                ? (mat[(size_t)s2 * nb + b] + bsum[((size_t)b * nseg + s2) >> 8]) : 0;
    }
    __syncthreads();
    int w = t >> 6, lane = t & 63;
    int s = blockIdx.x * WPB + w;
    if (s >= nseg) return;
    int* mycur = cur + w * nb;
    long long base = (long long)s * SEG;
    int cnt = (int)min((long long)SEG, (long long)e - base);
    for (int i = lane; i < cnt; i += 64) {
        long long ei = base + i;
        int src = load_idx(raw, f, ei);
        int d = load_idx(raw, f, (long long)e + ei);
        int b = d >> BIN_SHIFT;
        int pos = atomicAdd(&mycur[b], 1);
        packed[pos] = src | ((d & (BIN_NODES - 1)) << SRC_BITS);
    }
}

// Per-bin: wave-private LDS histogram -> scan -> dis/row_start + per-wave base
// cursors, then contention-free counting-sort to per-node CSR (recs = src, 4B).
// row_start[n] = e sentinel.
__global__ void degsort_kernel(const int* __restrict__ packed, const int* __restrict__ mat,
                               const int* __restrict__ bsum, float* __restrict__ dis,
                               int* __restrict__ row_start, int* __restrict__ recs,
                               int e, int n, int nb, int nseg) {
    __shared__ int cnt[WPB][BIN_NODES];
    __shared__ int wcur[WPB][BIN_NODES];
    __shared__ int exc[BIN_NODES];
    int b = blockIdx.x, t = threadIdx.x;
    int w = t >> 6, lane = t & 63;
    for (int i = t; i < WPB * BIN_NODES; i += 256) ((int*)cnt)[i] = 0;
    __syncthreads();
    int start = mat[b] + bsum[((size_t)b * nseg) >> 8];
    int end = (b + 1 < nb) ? (mat[b + 1] + bsum[((size_t)(b + 1) * nseg) >> 8]) : e;
    for (int i = start + w * 64 + lane; i < end; i += 256)
        atomicAdd(&cnt[w][packed[i] >> SRC_BITS], 1);
    __syncthreads();
    if (t < BIN_NODES) exc[t] = cnt[0][t] + cnt[1][t] + cnt[2][t] + cnt[3][t];
    __syncthreads();
    for (int off = 1; off < BIN_NODES; off <<= 1) {
        int v = 0;
        if (t < BIN_NODES && t >= off) v = exc[t - off];
        __syncthreads();
        if (t < BIN_NODES) exc[t] += v;
        __syncthreads();
    }
    if (t < BIN_NODES) {
        int c0 = cnt[0][t], c1 = cnt[1][t], c2 = cnt[2][t], c3 = cnt[3][t];
        int tot = c0 + c1 + c2 + c3;
        int rs = start + exc[t] - tot;   // inclusive -> exclusive
        wcur[0][t] = rs;
        wcur[1][t] = rs + c0;
        wcur[2][t] = rs + c0 + c1;
        wcur[3][t] = rs + c0 + c1 + c2;
        int node = b * BIN_NODES + t;
        if (node < n) {
            dis[node] = rsqrtf((float)tot + 1.0f);
            row_start[node] = rs;
        }
    }
    if (b == 0 && t == 128) row_start[n] = e;  // sentinel
    __syncthreads();
    for (int i = start + w * 64 + lane; i < end; i += 256) {
        int rec = packed[i];
        int pos = atomicAdd(&wcur[w][rec >> SRC_BITS], 1);
        recs[pos] = rec & SRC_MASK;
    }
}

// h~1 = fp16( dis * (x @ W1) )
__global__ void matmul_kernel(const float* __restrict__ in, const float* __restrict__ W,
                              const float* __restrict__ dis, __half* __restrict__ h,
                              int n) {
    __shared__ float Wl[FEAT * FEAT];
    int tid = threadIdx.x;
    for (int i = tid; i < FEAT * FEAT; i += 256) Wl[i] = W[i];
    __syncthreads();
    int node = blockIdx.x * 8 + (tid >> 5);
    int j = tid & 31;
    if (node >= n) return;
    float xv = in[node * FEAT + j];
    float sum = 0.0f;
#pragma unroll
    for (int k = 0; k < FEAT; ++k) sum = fmaf(__shfl(xv, k, 32), Wl[k * FEAT + j], sum);
    h[node * FEAT + j] = __float2half(dis[node] * sum);
}

// Fused pull1 + layer-2 matmul: per node, aggregate layer-1 messages, apply
// bias1+relu, multiply the 32-vector by W2 (shfl row broadcast), scale by dis,
// and emit h~2 in fp16. acc1 never touches memory.
__global__ __launch_bounds__(256, 4)
void pull1_kernel(const int* __restrict__ recs, const int* __restrict__ row_start,
                  const __half* __restrict__ h1, const float* __restrict__ dis,
                  const float* __restrict__ bias1, const float* __restrict__ W2,
                  __half* __restrict__ h2, int n) {
    __shared__ float Wl[FEAT * FEAT];
    __shared__ float bl[FEAT];
    int t = threadIdx.x;
    for (int i = t; i < FEAT * FEAT; i += 256) Wl[i] = W2[i];
    if (t < FEAT) bl[t] = bias1[t];
    __syncthreads();
    int node = blockIdx.x * 8 + (t >> 5);
    if (node >= n) return;
    int l32 = t & 31;
    int sub = l32 >> 3;   // record slot 0..3
    int fb = l32 & 7;     // 4-half feature block
    int start = row_start[node];
    int deg = row_start[node + 1] - start;
    const float2* g = (const float2*)h1;
    float4 sum = make_float4(0.0f, 0.0f, 0.0f, 0.0f);
    for (int r0 = 0; r0 < deg; r0 += 32) {
#pragma unroll
        for (int w = 0; w < 8; ++w) {
            int r = r0 + w * 4 + sub;
            if (r < deg) {
                int s = recs[start + r];
                float2 rv = g[(size_t)s * 8 + fb];
                float2 f01 = __half22float2(*(const __half2*)&rv.x);
                float2 f23 = __half22float2(*(const __half2*)&rv.y);
                sum.x += f01.x; sum.y += f01.y; sum.z += f23.x; sum.w += f23.y;
            }
        }
    }
    // butterfly: replicates sums to all 4 record slots
    sum.x += __shfl_xor(sum.x, 8, 64);  sum.y += __shfl_xor(sum.y, 8, 64);
    sum.z += __shfl_xor(sum.z, 8, 64);  sum.w += __shfl_xor(sum.w, 8, 64);
    sum.x += __shfl_xor(sum.x, 16, 64); sum.y += __shfl_xor(sum.y, 16, 64);
    sum.z += __shfl_xor(sum.z, 16, 64); sum.w += __shfl_xor(sum.w, 16, 64);
    float dn = dis[node];
    float2 rv = g[(size_t)node * 8 + fb];   // self-loop: + h~1[node]
    float2 f01 = __half22float2(*(const __half2*)&rv.x);
    float2 f23 = __half22float2(*(const __half2*)&rv.y);
    float4 a;   // relu(acc1) chunk for feats fb*4..fb*4+3 (replicated per sub)
    a.x = fmaxf(fmaf(dn, sum.x + f01.x, bl[fb * 4 + 0]), 0.0f);
    a.y = fmaxf(fmaf(dn, sum.y + f01.y, bl[fb * 4 + 1]), 0.0f);
    a.z = fmaxf(fmaf(dn, sum.z + f23.x, bl[fb * 4 + 2]), 0.0f);
    a.w = fmaxf(fmaf(dn, sum.w + f23.y, bl[fb * 4 + 3]), 0.0f);
    // row @ W2 via shfl broadcast from the sub==0 copy (lanes gb..gb+7)
    int gb = t & 32;   // wave-lane base of this 32-group
    float4 o = make_float4(0.0f, 0.0f, 0.0f, 0.0f);
#pragma unroll
    for (int k = 0; k < FEAT; ++k) {
        float comp = (k & 3) == 0 ? a.x : (k & 3) == 1 ? a.y : (k & 3) == 2 ? a.z : a.w;
        float ak = __shfl(comp, gb + (k >> 2), 64);
        const float* wr = &Wl[k * FEAT + fb * 4];
        o.x = fmaf(ak, wr[0], o.x);
        o.y = fmaf(ak, wr[1], o.y);
        o.z = fmaf(ak, wr[2], o.z);
        o.w = fmaf(ak, wr[3], o.w);
    }
    if (sub == 0) {
        union { __half2 hh[2]; float2 f; } u;
        u.hh[0] = __floats2half2_rn(dn * o.x, dn * o.y);
        u.hh[1] = __floats2half2_rn(dn * o.z, dn * o.w);
        ((float2*)h2)[(size_t)node * 8 + fb] = u.f;
    }
}

// Final pull: out[d] = relu( dis[d] * (sum h~2[s] + h~2[d]) + b2 ), fp32 out.
__global__ __launch_bounds__(256, 4)
void pull2_kernel(const int* __restrict__ recs, const int* __restrict__ row_start,
                  const __half* __restrict__ h2, const float* __restrict__ dis,
                  const float* __restrict__ bias2, float* __restrict__ out, int n) {
    int t = threadIdx.x;
    int node = blockIdx.x * 8 + (t >> 5);
    if (node >= n) return;
    int l32 = t & 31;
    int sub = l32 >> 3;
    int fb = l32 & 7;
    int start = row_start[node];
    int deg = row_start[node + 1] - start;
    const float2* g = (const float2*)h2;
    float4 sum = make_float4(0.0f, 0.0f, 0.0f, 0.0f);
    for (int r0 = 0; r0 < deg; r0 += 32) {
#pragma unroll
        for (int w = 0; w < 8; ++w) {
            int r = r0 + w * 4 + sub;
            if (r < deg) {
                int s = recs[start + r];
                float2 rv = g[(size_t)s * 8 + fb];
                float2 f01 = __half22float2(*(const __half2*)&rv.x);
                float2 f23 = __half22float2(*(const __half2*)&rv.y);
                sum.x += f01.x; sum.y += f01.y; sum.z += f23.x; sum.w += f23.y;
            }
        }
    }
    sum.x += __shfl_xor(sum.x, 8, 64);  sum.y += __shfl_xor(sum.y, 8, 64);
    sum.z += __shfl_xor(sum.z, 8, 64);  sum.w += __shfl_xor(sum.w, 8, 64);
    sum.x += __shfl_xor(sum.x, 16, 64); sum.y += __shfl_xor(sum.y, 16, 64);
    sum.z += __shfl_xor(sum.z, 16, 64); sum.w += __shfl_xor(sum.w, 16, 64);
    if (sub == 0) {
        float dn = dis[node];
        float2 rv = g[(size_t)node * 8 + fb];
        float2 f01 = __half22float2(*(const __half2*)&rv.x);
        float2 f23 = __half22float2(*(const __half2*)&rv.y);
        float4 bv = ((const float4*)bias2)[fb];
        float4 val;
        val.x = fmaxf(fmaf(dn, sum.x + f01.x, bv.x), 0.0f);
        val.y = fmaxf(fmaf(dn, sum.y + f01.y, bv.y), 0.0f);
        val.z = fmaxf(fmaf(dn, sum.z + f23.x, bv.z), 0.0f);
        val.w = fmaxf(fmaf(dn, sum.w + f23.y, bv.w), 0.0f);
        ((float4*)out)[(size_t)node * 8 + fb] = val;
    }
}

extern "C" void kernel_launch(void* const* d_in, const int* in_sizes, int n_in,
                              void* d_out, int out_size, void* d_ws, size_t ws_size,
                              hipStream_t stream) {
    const float* x = (const float*)d_in[0];
    const void* eidx_raw = d_in[1];
    const float* W1 = (const float*)d_in[2];
    const float* b1 = (const float*)d_in[3];
    const float* W2 = (const float*)d_in[4];
    const float* b2 = (const float*)d_in[5];
    float* out = (float*)d_out;

    const int n = in_sizes[0] / FEAT;                    // 100000
    const int e = in_sizes[1] / 2;                       // 1600000
    const int nb = (n + BIN_NODES - 1) / BIN_NODES;      // 782
    const int nseg = (e + SEG - 1) / SEG;                // 782
    const int M = nb * nseg;                             // ~612k
    const int nbks = (M + 255) / 256;                    // 2389 (scan2 K=3)
    const int gA = (nseg + WPB - 1) / WPB;               // 196

    // Workspace (256B-aligned). `packed` aliases `h1` (packed is dead after
    // degsort, before matmul writes h1).
    char* ws = (char*)d_ws;
    size_t off = 0;
    auto alloc = [&](size_t bytes) { char* p = ws + off; off = (off + bytes + 255) & ~(size_t)255; return p; };
    int*    mat       = (int*)   alloc((size_t)M * 4);
    int*    bsum      = (int*)   alloc((size_t)nbks * 4);
    float*  dis       = (float*) alloc((size_t)n * 4);
    int*    row_start = (int*)   alloc((size_t)(n + 1) * 4);
    int*    recs      = (int*)   alloc((size_t)e * 4);
    __half* h1        = (__half*)alloc((size_t)n * FEAT * 2);
    __half* h2        = (__half*)alloc((size_t)n * FEAT * 2);
    int*    packed    = (int*)h1;   // e*4 = 6.4MB == n*32*2

    const size_t lds_bins = (size_t)(WPB * nb + 1) * 4;  // 12.5 KB
    const int gNode = (n + 7) / 8;

    // CSR build (5 launches, wave-private LDS atomics only)
    binA_kernel<<<gA, 256, lds_bins, stream>>>(eidx_raw, mat, e, nb, nseg);
    scan1_kernel<<<nbks, 256, 0, stream>>>(mat, bsum, M, nb, nseg);
    scan2_kernel<<<1, 1024, 0, stream>>>(bsum, nbks);
    binC_kernel<<<gA, 256, lds_bins, stream>>>(eidx_raw, mat, bsum, packed, e, nb, nseg);
    degsort_kernel<<<nb, 256, 0, stream>>>(packed, mat, bsum, dis, row_start,
                                           recs, e, n, nb, nseg);

    // Layer 1 matmul, fused pull1+layer-2 matmul, final pull
    matmul_kernel<<<gNode, 256, 0, stream>>>(x, W1, dis, h1, n);
    pull1_kernel<<<gNode, 256, 0, stream>>>(recs, row_start, h1, dis, b1, W2, h2, n);
    pull2_kernel<<<gNode, 256, 0, stream>>>(recs, row_start, h2, dis, b2, out, n);
}

// Round 9
// 262.575 us; speedup vs baseline: 1.0238x; 1.0238x over previous
//
#include <hip/hip_runtime.h>
#include <hip/hip_fp16.h>

#define FEAT 32
#define BIN_NODES 128
#define BIN_SHIFT 7
#define SEG 2048          // edges per wave-segment
#define WPB 4             // wave-segments per block
#define SRC_BITS 20
#define SRC_MASK 0xFFFFF

// Block-local int64-vs-int32 detection: odd 32-bit words of an int64 index
// array (values < 2^31) are all zero; for int32 they are random node ids.
__device__ __forceinline__ int block_detect_int64(const int* __restrict__ raw32, int* nz) {
    if (threadIdx.x == 0) *nz = 0;
    __syncthreads();
    if (raw32[2 * threadIdx.x + 1] != 0) *nz = 1;
    __syncthreads();
    return (*nz == 0) ? 1 : 0;
}

__device__ __forceinline__ int load_idx(const void* raw, int f, long long i) {
    return f ? (int)((const long long*)raw)[i] : ((const int*)raw)[i];
}

// Phase A: per-(segment,bin) histogram, wave-private copies. Physical layout is
// bin-major: mat[b*nseg + s] so the later scan is coalesced (scan order == mem
// order). Writeout per bin = WPB consecutive ints (same cache line).
__global__ void binA_kernel(const void* __restrict__ raw, int* __restrict__ mat,
                            int e, int nb, int nseg) {
    extern __shared__ int hist[];  // WPB*nb + 1
    int t = threadIdx.x;
    for (int i = t; i < WPB * nb; i += 256) hist[i] = 0;
    int f = block_detect_int64((const int*)raw, &hist[WPB * nb]);  // syncs cover zeroing
    int w = t >> 6, lane = t & 63;
    int s = blockIdx.x * WPB + w;
    if (s < nseg) {
        int* hw = hist + w * nb;
        long long base = (long long)s * SEG;
        int cnt = (int)min((long long)SEG, (long long)e - base);
        for (int i = lane; i < cnt; i += 64) {
            int d = load_idx(raw, f, (long long)e + base + i);
            atomicAdd(&hw[d >> BIN_SHIFT], 1);
        }
    }
    __syncthreads();
    int s0 = blockIdx.x * WPB;
    for (int b = t; b < nb; b += 256)
#pragma unroll
        for (int w2 = 0; w2 < WPB; ++w2)
            if (s0 + w2 < nseg) mat[(size_t)b * nseg + s0 + w2] = hist[w2 * nb + b];
}

// Coalesced linear exclusive scan over mat (bin-major = scan order).
__global__ void scan1_kernel(int* __restrict__ mat, int* __restrict__ bsum, int M) {
    __shared__ int sd[256];
    int t = threadIdx.x;
    int L = blockIdx.x * 256 + t;
    int v = (L < M) ? mat[L] : 0;
    sd[t] = v;
    __syncthreads();
    for (int off = 1; off < 256; off <<= 1) {
        int add = (t >= off) ? sd[t - off] : 0;
        __syncthreads();
        sd[t] += add;
        __syncthreads();
    }
    if (L < M) mat[L] = sd[t] - v;   // exclusive within scan-block
    if (t == 255) bsum[blockIdx.x] = sd[t];
}

// Single-block scan, K elements per thread (K<=4 by construction).
__global__ void scan2_kernel(int* __restrict__ bsum, int nbks) {
    __shared__ int sd[1024];
    int t = threadIdx.x;
    int K = (nbks + 1023) >> 10;
    if (K > 4) K = 4;
    int base = t * K;
    int loc[4] = {0, 0, 0, 0};
    int s = 0;
    for (int k = 0; k < K; ++k) {
        int v = (base + k < nbks) ? bsum[base + k] : 0;
        loc[k] = s; s += v;
    }
    sd[t] = s;
    __syncthreads();
    for (int off = 1; off < 1024; off <<= 1) {
        int add = (t >= off) ? sd[t - off] : 0;
        __syncthreads();
        sd[t] += add;
        __syncthreads();
    }
    int excl = sd[t] - s;
    for (int k = 0; k < K; ++k) if (base + k < nbks) bsum[base + k] = excl + loc[k];
}

// Phase C: scatter packed records grouped by bin. Wave-private cursors (exact
// per-segment bases from the scan). rec = src | dst_local<<20.
__global__ void binC_kernel(const void* __restrict__ raw, const int* __restrict__ mat,
                            const int* __restrict__ bsum, int* __restrict__ packed,
                            int e, int nb, int nseg) {
    extern __shared__ int cur[];  // WPB*nb + 1
    int t = threadIdx.x;
    int f = block_detect_int64((const int*)raw, &cur[WPB * nb]);
    int s0 = blockIdx.x * WPB;
    for (int b = t; b < nb; b += 256)
#pragma unroll
        for (int w2 = 0; w2 < WPB; ++w2) {
            size_t p = (size_t)b * nseg + s0 + w2;
            cur[w2 * nb + b] = (s0 + w2 < nseg) ? (mat[p] + bsum[p >> 8]) : 0;
        }
    __syncthreads();
    int w = t >> 6, lane = t & 63;
    int s = s0 + w;
    if (s >= nseg) return;
    int* mycur = cur + w * nb;
    long long base = (long long)s * SEG;
    int cnt = (int)min((long long)SEG, (long long)e - base);
    for (int i = lane; i < cnt; i += 64) {
        long long ei = base + i;
        int src = load_idx(raw, f, ei);
        int d = load_idx(raw, f, (long long)e + ei);
        int b = d >> BIN_SHIFT;
        int pos = atomicAdd(&mycur[b], 1);
        packed[pos] = src | ((d & (BIN_NODES - 1)) << SRC_BITS);
    }
}

// Per-bin: wave-private LDS histogram -> scan -> dis/row_start + per-wave base
// cursors, then contention-free counting-sort to per-node CSR (recs = src, 4B).
__global__ void degsort_kernel(const int* __restrict__ packed, const int* __restrict__ mat,
                               const int* __restrict__ bsum, float* __restrict__ dis,
                               int* __restrict__ row_start, int* __restrict__ recs,
                               int e, int n, int nb, int nseg) {
    __shared__ int cnt[WPB][BIN_NODES];
    __shared__ int wcur[WPB][BIN_NODES];
    __shared__ int exc[BIN_NODES];
    int b = blockIdx.x, t = threadIdx.x;
    int w = t >> 6, lane = t & 63;
    for (int i = t; i < WPB * BIN_NODES; i += 256) ((int*)cnt)[i] = 0;
    __syncthreads();
    size_t p0 = (size_t)b * nseg;
    int start = mat[p0] + bsum[p0 >> 8];
    size_t p1 = (size_t)(b + 1) * nseg;
    int end = (b + 1 < nb) ? (mat[p1] + bsum[p1 >> 8]) : e;
    for (int i = start + w * 64 + lane; i < end; i += 256)
        atomicAdd(&cnt[w][packed[i] >> SRC_BITS], 1);
    __syncthreads();
    if (t < BIN_NODES) exc[t] = cnt[0][t] + cnt[1][t] + cnt[2][t] + cnt[3][t];
    __syncthreads();
    for (int off = 1; off < BIN_NODES; off <<= 1) {
        int v = 0;
        if (t < BIN_NODES && t >= off) v = exc[t - off];
        __syncthreads();
        if (t < BIN_NODES) exc[t] += v;
        __syncthreads();
    }
    if (t < BIN_NODES) {
        int c0 = cnt[0][t], c1 = cnt[1][t], c2 = cnt[2][t], c3 = cnt[3][t];
        int tot = c0 + c1 + c2 + c3;
        int rs = start + exc[t] - tot;   // inclusive -> exclusive
        wcur[0][t] = rs;
        wcur[1][t] = rs + c0;
        wcur[2][t] = rs + c0 + c1;
        wcur[3][t] = rs + c0 + c1 + c2;
        int node = b * BIN_NODES + t;
        if (node < n) {
            dis[node] = rsqrtf((float)tot + 1.0f);
            row_start[node] = rs;
        }
    }
    if (b == 0 && t == 128) row_start[n] = e;  // sentinel
    __syncthreads();
    for (int i = start + w * 64 + lane; i < end; i += 256) {
        int rec = packed[i];
        int pos = atomicAdd(&wcur[w][rec >> SRC_BITS], 1);
        recs[pos] = rec & SRC_MASK;
    }
}

// h~ = fp16( dis * (act(in) @ W) )   (8 nodes x 32 lanes per block, W in LDS)
__global__ void matmul_kernel(const float* __restrict__ in, const float* __restrict__ W,
                              const float* __restrict__ dis, __half* __restrict__ h,
                              int n, int relu_in) {
    __shared__ float Wl[FEAT * FEAT];
    int tid = threadIdx.x;
    for (int i = tid; i < FEAT * FEAT; i += 256) Wl[i] = W[i];
    __syncthreads();
    int node = blockIdx.x * 8 + (tid >> 5);
    int j = tid & 31;
    if (node >= n) return;
    float xv = in[node * FEAT + j];
    if (relu_in) xv = fmaxf(xv, 0.0f);
    float sum = 0.0f;
#pragma unroll
    for (int k = 0; k < FEAT; ++k) sum = fmaf(__shfl(xv, k, 32), Wl[k * FEAT + j], sum);
    h[node * FEAT + j] = __float2half(dis[node] * sum);
}

// Pull: out[d] = act( dis[d] * (sum_{s in N(d)} h~[s] + h~[d]) + bias ).
// 32 lanes/node = 4 record-slots x 8 feature-lanes (4 halves = 8B each);
// one record's gather = 64B = 1 cache line; 8 predicated gathers in flight.
// Lean kernel, launch_bounds(256,8) for full occupancy (latency-bound).
__global__ __launch_bounds__(256, 8)
void pull_kernel(const int* __restrict__ recs, const int* __restrict__ row_start,
                 const __half* __restrict__ h, const float* __restrict__ dis,
                 const float* __restrict__ bias, float* __restrict__ out,
                 int n, int relu_out) {
    int t = threadIdx.x;
    int node = blockIdx.x * 8 + (t >> 5);
    if (node >= n) return;
    int l32 = t & 31;
    int sub = l32 >> 3;   // record slot 0..3
    int fb = l32 & 7;     // 4-half feature block
    int start = row_start[node];
    int deg = row_start[node + 1] - start;
    const float2* h2 = (const float2*)h;  // 4 halves per float2
    float4 sum = make_float4(0.0f, 0.0f, 0.0f, 0.0f);
    for (int r0 = 0; r0 < deg; r0 += 32) {
#pragma unroll
        for (int w = 0; w < 8; ++w) {
            int r = r0 + w * 4 + sub;
            if (r < deg) {
                int s = recs[start + r];
                float2 rv = h2[(size_t)s * 8 + fb];
                float2 f01 = __half22float2(*(const __half2*)&rv.x);
                float2 f23 = __half22float2(*(const __half2*)&rv.y);
                sum.x += f01.x; sum.y += f01.y; sum.z += f23.x; sum.w += f23.y;
            }
        }
    }
    sum.x += __shfl_xor(sum.x, 8, 64);  sum.y += __shfl_xor(sum.y, 8, 64);
    sum.z += __shfl_xor(sum.z, 8, 64);  sum.w += __shfl_xor(sum.w, 8, 64);
    sum.x += __shfl_xor(sum.x, 16, 64); sum.y += __shfl_xor(sum.y, 16, 64);
    sum.z += __shfl_xor(sum.z, 16, 64); sum.w += __shfl_xor(sum.w, 16, 64);
    if (sub == 0) {
        float dn = dis[node];
        float2 rv = h2[(size_t)node * 8 + fb];   // self-loop: + h~[node]
        float2 f01 = __half22float2(*(const __half2*)&rv.x);
        float2 f23 = __half22float2(*(const __half2*)&rv.y);
        float4 bv = ((const float4*)bias)[fb];
        float4 val;
        val.x = fmaf(dn, sum.x + f01.x, bv.x);
        val.y = fmaf(dn, sum.y + f01.y, bv.y);
        val.z = fmaf(dn, sum.z + f23.x, bv.z);
        val.w = fmaf(dn, sum.w + f23.y, bv.w);
        if (relu_out) {
            val.x = fmaxf(val.x, 0.0f); val.y = fmaxf(val.y, 0.0f);
            val.z = fmaxf(val.z, 0.0f); val.w = fmaxf(val.w, 0.0f);
        }
        ((float4*)out)[(size_t)node * 8 + fb] = val;
    }
}

extern "C" void kernel_launch(void* const* d_in, const int* in_sizes, int n_in,
                              void* d_out, int out_size, void* d_ws, size_t ws_size,
                              hipStream_t stream) {
    const float* x = (const float*)d_in[0];
    const void* eidx_raw = d_in[1];
    const float* W1 = (const float*)d_in[2];
    const float* b1 = (const float*)d_in[3];
    const float* W2 = (const float*)d_in[4];
    const float* b2 = (const float*)d_in[5];
    float* out = (float*)d_out;

    const int n = in_sizes[0] / FEAT;                    // 100000
    const int e = in_sizes[1] / 2;                       // 1600000
    const int nb = (n + BIN_NODES - 1) / BIN_NODES;      // 782
    const int nseg = (e + SEG - 1) / SEG;                // 782
    const int M = nb * nseg;                             // ~612k
    const int nbks = (M + 255) / 256;                    // 2389 (scan2 K=3)
    const int gA = (nseg + WPB - 1) / WPB;               // 196

    // Workspace (256B-aligned). `packed` aliases `acc1` (packed dead after
    // degsort, acc1 first written by pull1).
    char* ws = (char*)d_ws;
    size_t off = 0;
    auto alloc = [&](size_t bytes) { char* p = ws + off; off = (off + bytes + 255) & ~(size_t)255; return p; };
    int*    mat       = (int*)   alloc((size_t)M * 4);
    int*    bsum      = (int*)   alloc((size_t)nbks * 4);
    float*  dis       = (float*) alloc((size_t)n * 4);
    int*    row_start = (int*)   alloc((size_t)(n + 1) * 4);
    int*    recs      = (int*)   alloc((size_t)e * 4);
    __half* h         = (__half*)alloc((size_t)n * FEAT * 2);
    float*  acc1      = (float*) alloc((size_t)n * FEAT * 4);
    int*    packed    = (int*)acc1;   // e*4 = 6.4MB <= 12.8MB

    const size_t lds_bins = (size_t)(WPB * nb + 1) * 4;  // 12.5 KB
    const int gNode = (n + 7) / 8;

    // CSR build (5 launches, wave-private LDS atomics, coalesced scan)
    binA_kernel<<<gA, 256, lds_bins, stream>>>(eidx_raw, mat, e, nb, nseg);
    scan1_kernel<<<nbks, 256, 0, stream>>>(mat, bsum, M);
    scan2_kernel<<<1, 1024, 0, stream>>>(bsum, nbks);
    binC_kernel<<<gA, 256, lds_bins, stream>>>(eidx_raw, mat, bsum, packed, e, nb, nseg);
    degsort_kernel<<<nb, 256, 0, stream>>>(packed, mat, bsum, dis, row_start,
                                           recs, e, n, nb, nseg);

    // Layer 1
    matmul_kernel<<<gNode, 256, 0, stream>>>(x, W1, dis, h, n, 0);
    pull_kernel<<<gNode, 256, 0, stream>>>(recs, row_start, h, dis, b1, acc1, n, 0);

    // Layer 2 (relu on read of acc1; final relu fused in writeout)
    matmul_kernel<<<gNode, 256, 0, stream>>>(acc1, W2, dis, h, n, 1);
    pull_kernel<<<gNode, 256, 0, stream>>>(recs, row_start, h, dis, b2, out, n, 1);
}

// Round 10
// 243.603 us; speedup vs baseline: 1.1035x; 1.0779x over previous
//
#include <hip/hip_runtime.h>
#include <hip/hip_fp16.h>

#define FEAT 32
#define BIN_NODES 128
#define BIN_SHIFT 7
#define TILE_EDGES 8192   // edges per build block
#define BWAVES 16         // waves per build block (1024 threads)
#define SRC_BITS 20
#define SRC_MASK 0xFFFFF

// Block-local int64-vs-int32 detection: odd 32-bit words of an int64 index
// array (values < 2^31) are all zero; for int32 they are random node ids.
__device__ __forceinline__ int block_detect_int64(const int* __restrict__ raw32, int* nz,
                                                  int nthreads) {
    if (threadIdx.x == 0) *nz = 0;
    __syncthreads();
    if (raw32[2 * threadIdx.x + 1] != 0) *nz = 1;
    __syncthreads();
    (void)nthreads;
    return (*nz == 0) ? 1 : 0;
}

__device__ __forceinline__ int load_idx(const void* raw, int f, long long i) {
    return f ? (int)((const long long*)raw)[i] : ((const int*)raw)[i];
}

// Phase A: per-(tile,bin) histogram, 16 wave-private copies (1024 threads).
// mat layout: mat[k*nb + b] (tile-major, round-7 proven). Writeout merges the
// 16 copies, coalesced across b.
__global__ __launch_bounds__(1024)
void binA_kernel(const void* __restrict__ raw, int* __restrict__ mat, int e, int nb) {
    extern __shared__ int hist[];  // BWAVES*nb + 1
    int t = threadIdx.x;
    for (int i = t; i < BWAVES * nb; i += 1024) hist[i] = 0;
    int f = block_detect_int64((const int*)raw, &hist[BWAVES * nb], 1024);
    int w = t >> 6, lane = t & 63;
    long long base = (long long)blockIdx.x * TILE_EDGES;
    int cnt = (int)min((long long)TILE_EDGES, (long long)e - base);
    int* hw = hist + w * nb;
    const int seg = TILE_EDGES / BWAVES;  // 512 edges per wave
    int wbeg = w * seg;
    int wend = min(wbeg + seg, cnt);
    for (int i = wbeg + lane; i < wend; i += 64) {
        int d = load_idx(raw, f, (long long)e + base + i);
        atomicAdd(&hw[d >> BIN_SHIFT], 1);
    }
    __syncthreads();
    for (int b = t; b < nb; b += 1024) {
        int s = 0;
#pragma unroll
        for (int w2 = 0; w2 < BWAVES; ++w2) s += hist[w2 * nb + b];
        mat[blockIdx.x * nb + b] = s;
    }
}

// logical L = b*nblk + k (bin-major) <-> physical p = k*nb + b
__device__ __forceinline__ int l2p(int L, int nb, int nblk) {
    int b = L / nblk;
    int k = L - b * nblk;
    return k * nb + b;
}

__global__ void scan1_kernel(int* __restrict__ mat, int* __restrict__ bsum,
                             int M, int nb, int nblk) {
    __shared__ int sd[256];
    int t = threadIdx.x;
    int L = blockIdx.x * 256 + t;
    int p = 0, v = 0;
    if (L < M) { p = l2p(L, nb, nblk); v = mat[p]; }
    sd[t] = v;
    __syncthreads();
    for (int off = 1; off < 256; off <<= 1) {
        int add = (t >= off) ? sd[t - off] : 0;
        __syncthreads();
        sd[t] += add;
        __syncthreads();
    }
    if (L < M) mat[p] = sd[t] - v;   // exclusive within scan-block
    if (t == 255) bsum[blockIdx.x] = sd[t];
}

__global__ void scan2_kernel(int* __restrict__ bsum, int nbks) {
    __shared__ int sd[1024];
    int t = threadIdx.x;
    int v = (t < nbks) ? bsum[t] : 0;
    sd[t] = v;
    __syncthreads();
    for (int off = 1; off < 1024; off <<= 1) {
        int add = (t >= off) ? sd[t - off] : 0;
        __syncthreads();
        sd[t] += add;
        __syncthreads();
    }
    if (t < nbks) bsum[t] = sd[t] - v;
}

// Phase C: scatter packed records grouped by bin (1024 threads; block-shared
// cursors — conflict cycles measured negligible). rec = src | dst_local<<20.
__global__ __launch_bounds__(1024)
void binC_kernel(const void* __restrict__ raw, const int* __restrict__ mat,
                 const int* __restrict__ bsum, int* __restrict__ packed,
                 int e, int nb, int nblk) {
    extern __shared__ int cur[];  // nb + 1
    int t = threadIdx.x;
    int f = block_detect_int64((const int*)raw, &cur[nb], 1024);
    for (int i = t; i < nb; i += 1024)
        cur[i] = mat[blockIdx.x * nb + i] + bsum[(i * nblk + blockIdx.x) >> 8];
    __syncthreads();
    long long base = (long long)blockIdx.x * TILE_EDGES;
    int cnt = (int)min((long long)TILE_EDGES, (long long)e - base);
    for (int i = t; i < cnt; i += 1024) {
        long long ei = base + i;
        int s = load_idx(raw, f, ei);
        int d = load_idx(raw, f, (long long)e + ei);
        int b = d >> BIN_SHIFT;
        int pos = atomicAdd(&cur[b], 1);
        packed[pos] = s | ((d & (BIN_NODES - 1)) << SRC_BITS);
    }
}

// Per-bin: 16 wave-private LDS histograms -> scan -> dis/row_start + per-wave
// base cursors, then contention-free counting-sort (recs = src, 4B).
__global__ __launch_bounds__(1024)
void degsort_kernel(const int* __restrict__ packed, const int* __restrict__ mat,
                    const int* __restrict__ bsum, float* __restrict__ dis,
                    int* __restrict__ row_start, int* __restrict__ recs,
                    int e, int n, int nb, int nblk) {
    __shared__ int cnt[BWAVES][BIN_NODES];
    __shared__ int wcur[BWAVES][BIN_NODES];
    __shared__ int exc[BIN_NODES];
    int b = blockIdx.x, t = threadIdx.x;
    int w = t >> 6;
    for (int i = t; i < BWAVES * BIN_NODES; i += 1024) ((int*)cnt)[i] = 0;
    __syncthreads();
    int start = mat[b] + bsum[(b * nblk) >> 8];
    int end = (b + 1 < nb) ? (mat[b + 1] + bsum[((b + 1) * nblk) >> 8]) : e;
    for (int i = start + t; i < end; i += 1024)
        atomicAdd(&cnt[w][packed[i] >> SRC_BITS], 1);
    __syncthreads();
    if (t < BIN_NODES) {
        int s = 0;
#pragma unroll
        for (int w2 = 0; w2 < BWAVES; ++w2) s += cnt[w2][t];
        exc[t] = s;
    }
    __syncthreads();
    for (int off = 1; off < BIN_NODES; off <<= 1) {
        int v = 0;
        if (t < BIN_NODES && t >= off) v = exc[t - off];
        __syncthreads();
        if (t < BIN_NODES) exc[t] += v;
        __syncthreads();
    }
    if (t < BIN_NODES) {
        int tot = 0;
#pragma unroll
        for (int w2 = 0; w2 < BWAVES; ++w2) tot += cnt[w2][t];
        int rs = start + exc[t] - tot;   // inclusive -> exclusive
        int run = rs;
#pragma unroll
        for (int w2 = 0; w2 < BWAVES; ++w2) { wcur[w2][t] = run; run += cnt[w2][t]; }
        int node = b * BIN_NODES + t;
        if (node < n) {
            dis[node] = rsqrtf((float)tot + 1.0f);
            row_start[node] = rs;
        }
    }
    if (b == 0 && t == 128) row_start[n] = e;  // sentinel
    __syncthreads();
    for (int i = start + t; i < end; i += 1024) {
        int rec = packed[i];
        int pos = atomicAdd(&wcur[w][rec >> SRC_BITS], 1);
        recs[pos] = rec & SRC_MASK;
    }
}

// h~ = fp16( dis * (act(in) @ W) )   (8 nodes x 32 lanes per block, W in LDS)
__global__ void matmul_kernel(const float* __restrict__ in, const float* __restrict__ W,
                              const float* __restrict__ dis, __half* __restrict__ h,
                              int n, int relu_in) {
    __shared__ float Wl[FEAT * FEAT];
    int tid = threadIdx.x;
    for (int i = tid; i < FEAT * FEAT; i += 256) Wl[i] = W[i];
    __syncthreads();
    int node = blockIdx.x * 8 + (tid >> 5);
    int j = tid & 31;
    if (node >= n) return;
    float xv = in[node * FEAT + j];
    if (relu_in) xv = fmaxf(xv, 0.0f);
    float sum = 0.0f;
#pragma unroll
    for (int k = 0; k < FEAT; ++k) sum = fmaf(__shfl(xv, k, 32), Wl[k * FEAT + j], sum);
    h[node * FEAT + j] = __float2half(dis[node] * sum);
}

// Pull: out[d] = act( dis[d] * (sum_{s in N(d)} h~[s] + h~[d]) + bias ).
// 32 lanes/node = 4 record-slots x 8 feature-lanes (4 halves = 8B each);
// one record's gather = 64B = 1 cache line; 8 predicated gathers in flight.
__global__ __launch_bounds__(256, 4)
void pull_kernel(const int* __restrict__ recs, const int* __restrict__ row_start,
                 const __half* __restrict__ h, const float* __restrict__ dis,
                 const float* __restrict__ bias, float* __restrict__ out,
                 int n, int relu_out) {
    int t = threadIdx.x;
    int node = blockIdx.x * 8 + (t >> 5);
    if (node >= n) return;
    int l32 = t & 31;
    int sub = l32 >> 3;   // record slot 0..3
    int fb = l32 & 7;     // 4-half feature block
    int start = row_start[node];
    int deg = row_start[node + 1] - start;
    const float2* h2 = (const float2*)h;  // 4 halves per float2
    float4 sum = make_float4(0.0f, 0.0f, 0.0f, 0.0f);
    for (int r0 = 0; r0 < deg; r0 += 32) {
#pragma unroll
        for (int w = 0; w < 8; ++w) {
            int r = r0 + w * 4 + sub;
            if (r < deg) {
                int s = recs[start + r];
                float2 rv = h2[(size_t)s * 8 + fb];
                float2 f01 = __half22float2(*(const __half2*)&rv.x);
                float2 f23 = __half22float2(*(const __half2*)&rv.y);
                sum.x += f01.x; sum.y += f01.y; sum.z += f23.x; sum.w += f23.y;
            }
        }
    }
    sum.x += __shfl_xor(sum.x, 8, 64);  sum.y += __shfl_xor(sum.y, 8, 64);
    sum.z += __shfl_xor(sum.z, 8, 64);  sum.w += __shfl_xor(sum.w, 8, 64);
    sum.x += __shfl_xor(sum.x, 16, 64); sum.y += __shfl_xor(sum.y, 16, 64);
    sum.z += __shfl_xor(sum.z, 16, 64); sum.w += __shfl_xor(sum.w, 16, 64);
    if (sub == 0) {
        float dn = dis[node];
        float2 rv = h2[(size_t)node * 8 + fb];   // self-loop: + h~[node]
        float2 f01 = __half22float2(*(const __half2*)&rv.x);
        float2 f23 = __half22float2(*(const __half2*)&rv.y);
        float4 bv = ((const float4*)bias)[fb];
        float4 val;
        val.x = fmaf(dn, sum.x + f01.x, bv.x);
        val.y = fmaf(dn, sum.y + f01.y, bv.y);
        val.z = fmaf(dn, sum.z + f23.x, bv.z);
        val.w = fmaf(dn, sum.w + f23.y, bv.w);
        if (relu_out) {
            val.x = fmaxf(val.x, 0.0f); val.y = fmaxf(val.y, 0.0f);
            val.z = fmaxf(val.z, 0.0f); val.w = fmaxf(val.w, 0.0f);
        }
        ((float4*)out)[(size_t)node * 8 + fb] = val;
    }
}

extern "C" void kernel_launch(void* const* d_in, const int* in_sizes, int n_in,
                              void* d_out, int out_size, void* d_ws, size_t ws_size,
                              hipStream_t stream) {
    const float* x = (const float*)d_in[0];
    const void* eidx_raw = d_in[1];
    const float* W1 = (const float*)d_in[2];
    const float* b1 = (const float*)d_in[3];
    const float* W2 = (const float*)d_in[4];
    const float* b2 = (const float*)d_in[5];
    float* out = (float*)d_out;

    const int n = in_sizes[0] / FEAT;                    // 100000
    const int e = in_sizes[1] / 2;                       // 1600000
    const int nb = (n + BIN_NODES - 1) / BIN_NODES;      // 782
    const int nblk = (e + TILE_EDGES - 1) / TILE_EDGES;  // 196
    const int M = nb * nblk;                             // 153k
    const int nbks = (M + 255) / 256;                    // 599 <= 1024

    // Workspace (256B-aligned). `packed` aliases `acc1` (packed dead after
    // degsort, acc1 first written by pull1).
    char* ws = (char*)d_ws;
    size_t off = 0;
    auto alloc = [&](size_t bytes) { char* p = ws + off; off = (off + bytes + 255) & ~(size_t)255; return p; };
    int*    mat       = (int*)   alloc((size_t)M * 4);
    int*    bsum      = (int*)   alloc((size_t)nbks * 4);
    float*  dis       = (float*) alloc((size_t)n * 4);
    int*    row_start = (int*)   alloc((size_t)(n + 1) * 4);
    int*    recs      = (int*)   alloc((size_t)e * 4);
    __half* h         = (__half*)alloc((size_t)n * FEAT * 2);
    float*  acc1      = (float*) alloc((size_t)n * FEAT * 4);
    int*    packed    = (int*)acc1;   // e*4 = 6.4MB <= 12.8MB

    const size_t ldsA = (size_t)(BWAVES * nb + 1) * 4;   // ~50 KB
    const size_t ldsC = (size_t)(nb + 1) * 4;            // ~3.1 KB
    const int gNode = (n + 7) / 8;

    // CSR build: round-7 layout, 4x wave parallelism in binA/binC/degsort
    binA_kernel<<<nblk, 1024, ldsA, stream>>>(eidx_raw, mat, e, nb);
    scan1_kernel<<<nbks, 256, 0, stream>>>(mat, bsum, M, nb, nblk);
    scan2_kernel<<<1, 1024, 0, stream>>>(bsum, nbks);
    binC_kernel<<<nblk, 1024, ldsC, stream>>>(eidx_raw, mat, bsum, packed, e, nb, nblk);
    degsort_kernel<<<nb, 1024, 0, stream>>>(packed, mat, bsum, dis, row_start,
                                            recs, e, n, nb, nblk);

    // Layer 1
    matmul_kernel<<<gNode, 256, 0, stream>>>(x, W1, dis, h, n, 0);
    pull_kernel<<<gNode, 256, 0, stream>>>(recs, row_start, h, dis, b1, acc1, n, 0);

    // Layer 2 (relu on read of acc1; final relu fused in writeout)
    matmul_kernel<<<gNode, 256, 0, stream>>>(acc1, W2, dis, h, n, 1);
    pull_kernel<<<gNode, 256, 0, stream>>>(recs, row_start, h, dis, b2, out, n, 1);
}

// Round 11
// 228.094 us; speedup vs baseline: 1.1786x; 1.0680x over previous
//
#include <hip/hip_runtime.h>
#include <hip/hip_fp16.h>

#define FEAT 32
#define BIN_NODES 128
#define BIN_SHIFT 7
#define TILE_EDGES 8192   // edges per build block
#define BWAVES 16         // waves per build block (1024 threads)
#define SRC_BITS 20
#define SRC_MASK 0xFFFFF

// Block-local int64-vs-int32 detection: odd 32-bit words of an int64 index
// array (values < 2^31) are all zero; for int32 they are random node ids.
__device__ __forceinline__ int block_detect_int64(const int* __restrict__ raw32, int* nz) {
    if (threadIdx.x == 0) *nz = 0;
    __syncthreads();
    if (raw32[2 * threadIdx.x + 1] != 0) *nz = 1;
    __syncthreads();
    return (*nz == 0) ? 1 : 0;
}

__device__ __forceinline__ int load_idx(const void* raw, int f, long long i) {
    return f ? (int)((const long long*)raw)[i] : ((const int*)raw)[i];
}

// Phase A: per-(tile,bin) histogram, 16 wave-private copies (1024 threads).
// mat layout: mat[k*nb + b] (tile-major). Writeout merges the 16 copies.
__global__ __launch_bounds__(1024)
void binA_kernel(const void* __restrict__ raw, int* __restrict__ mat, int e, int nb) {
    extern __shared__ int hist[];  // BWAVES*nb + 1
    int t = threadIdx.x;
    for (int i = t; i < BWAVES * nb; i += 1024) hist[i] = 0;
    int f = block_detect_int64((const int*)raw, &hist[BWAVES * nb]);
    int w = t >> 6, lane = t & 63;
    long long base = (long long)blockIdx.x * TILE_EDGES;
    int cnt = (int)min((long long)TILE_EDGES, (long long)e - base);
    int* hw = hist + w * nb;
    const int seg = TILE_EDGES / BWAVES;  // 512 edges per wave
    int wbeg = w * seg;
    int wend = min(wbeg + seg, cnt);
    for (int i = wbeg + lane; i < wend; i += 64) {
        int d = load_idx(raw, f, (long long)e + base + i);
        atomicAdd(&hw[d >> BIN_SHIFT], 1);
    }
    __syncthreads();
    for (int b = t; b < nb; b += 1024) {
        int s = 0;
#pragma unroll
        for (int w2 = 0; w2 < BWAVES; ++w2) s += hist[w2 * nb + b];
        mat[blockIdx.x * nb + b] = s;
    }
}

// logical L = b*nblk + k (bin-major) <-> physical p = k*nb + b
__device__ __forceinline__ int l2p(int L, int nb, int nblk) {
    int b = L / nblk;
    int k = L - b * nblk;
    return k * nb + b;
}

__global__ void scan1_kernel(int* __restrict__ mat, int* __restrict__ bsum,
                             int M, int nb, int nblk) {
    __shared__ int sd[256];
    int t = threadIdx.x;
    int L = blockIdx.x * 256 + t;
    int p = 0, v = 0;
    if (L < M) { p = l2p(L, nb, nblk); v = mat[p]; }
    sd[t] = v;
    __syncthreads();
    for (int off = 1; off < 256; off <<= 1) {
        int add = (t >= off) ? sd[t - off] : 0;
        __syncthreads();
        sd[t] += add;
        __syncthreads();
    }
    if (L < M) mat[p] = sd[t] - v;   // exclusive within scan-block
    if (t == 255) bsum[blockIdx.x] = sd[t];
}

__global__ void scan2_kernel(int* __restrict__ bsum, int nbks) {
    __shared__ int sd[1024];
    int t = threadIdx.x;
    int v = (t < nbks) ? bsum[t] : 0;
    sd[t] = v;
    __syncthreads();
    for (int off = 1; off < 1024; off <<= 1) {
        int add = (t >= off) ? sd[t - off] : 0;
        __syncthreads();
        sd[t] += add;
        __syncthreads();
    }
    if (t < nbks) bsum[t] = sd[t] - v;
}

// Phase C: scatter packed records grouped by bin (1024 threads; block-shared
// cursors — conflict cycles measured negligible). rec = src | dst_local<<20.
__global__ __launch_bounds__(1024)
void binC_kernel(const void* __restrict__ raw, const int* __restrict__ mat,
                 const int* __restrict__ bsum, int* __restrict__ packed,
                 int e, int nb, int nblk) {
    extern __shared__ int cur[];  // nb + 1
    int t = threadIdx.x;
    int f = block_detect_int64((const int*)raw, &cur[nb]);
    for (int i = t; i < nb; i += 1024)
        cur[i] = mat[blockIdx.x * nb + i] + bsum[(i * nblk + blockIdx.x) >> 8];
    __syncthreads();
    long long base = (long long)blockIdx.x * TILE_EDGES;
    int cnt = (int)min((long long)TILE_EDGES, (long long)e - base);
    for (int i = t; i < cnt; i += 1024) {
        long long ei = base + i;
        int s = load_idx(raw, f, ei);
        int d = load_idx(raw, f, (long long)e + ei);
        int b = d >> BIN_SHIFT;
        int pos = atomicAdd(&cur[b], 1);
        packed[pos] = s | ((d & (BIN_NODES - 1)) << SRC_BITS);
    }
}

// Per-bin: 16 wave-private LDS histograms -> scan -> dis/row_start + per-wave
// base cursors, then contention-free counting-sort (recs = src, 4B).
__global__ __launch_bounds__(1024)
void degsort_kernel(const int* __restrict__ packed, const int* __restrict__ mat,
                    const int* __restrict__ bsum, float* __restrict__ dis,
                    int* __restrict__ row_start, int* __restrict__ recs,
                    int e, int n, int nb, int nblk) {
    __shared__ int cnt[BWAVES][BIN_NODES];
    __shared__ int wcur[BWAVES][BIN_NODES];
    __shared__ int exc[BIN_NODES];
    int b = blockIdx.x, t = threadIdx.x;
    int w = t >> 6;
    for (int i = t; i < BWAVES * BIN_NODES; i += 1024) ((int*)cnt)[i] = 0;
    __syncthreads();
    int start = mat[b] + bsum[(b * nblk) >> 8];
    int end = (b + 1 < nb) ? (mat[b + 1] + bsum[((b + 1) * nblk) >> 8]) : e;
    for (int i = start + t; i < end; i += 1024)
        atomicAdd(&cnt[w][packed[i] >> SRC_BITS], 1);
    __syncthreads();
    if (t < BIN_NODES) {
        int s = 0;
#pragma unroll
        for (int w2 = 0; w2 < BWAVES; ++w2) s += cnt[w2][t];
        exc[t] = s;
    }
    __syncthreads();
    for (int off = 1; off < BIN_NODES; off <<= 1) {
        int v = 0;
        if (t < BIN_NODES && t >= off) v = exc[t - off];
        __syncthreads();
        if (t < BIN_NODES) exc[t] += v;
        __syncthreads();
    }
    if (t < BIN_NODES) {
        int tot = 0;
#pragma unroll
        for (int w2 = 0; w2 < BWAVES; ++w2) tot += cnt[w2][t];
        int rs = start + exc[t] - tot;   // inclusive -> exclusive
        int run = rs;
#pragma unroll
        for (int w2 = 0; w2 < BWAVES; ++w2) { wcur[w2][t] = run; run += cnt[w2][t]; }
        int node = b * BIN_NODES + t;
        if (node < n) {
            dis[node] = rsqrtf((float)tot + 1.0f);
            row_start[node] = rs;
        }
    }
    if (b == 0 && t == 128) row_start[n] = e;  // sentinel
    __syncthreads();
    for (int i = start + t; i < end; i += 1024) {
        int rec = packed[i];
        int pos = atomicAdd(&wcur[w][rec >> SRC_BITS], 1);
        recs[pos] = rec & SRC_MASK;
    }
}

// h~ = fp16( dis * (act(in) @ W) )   (8 nodes x 32 lanes per block, W in LDS)
__global__ void matmul_kernel(const float* __restrict__ in, const float* __restrict__ W,
                              const float* __restrict__ dis, __half* __restrict__ h,
                              int n, int relu_in) {
    __shared__ float Wl[FEAT * FEAT];
    int tid = threadIdx.x;
    for (int i = tid; i < FEAT * FEAT; i += 256) Wl[i] = W[i];
    __syncthreads();
    int node = blockIdx.x * 8 + (tid >> 5);
    int j = tid & 31;
    if (node >= n) return;
    float xv = in[node * FEAT + j];
    if (relu_in) xv = fmaxf(xv, 0.0f);
    float sum = 0.0f;
#pragma unroll
    for (int k = 0; k < FEAT; ++k) sum = fmaf(__shfl(xv, k, 32), Wl[k * FEAT + j], sum);
    h[node * FEAT + j] = __float2half(dis[node] * sum);
}

// Pull: out[d] = act( dis[d] * (sum_{s in N(d)} h~[s] + h~[d]) + bias ).
// 32 lanes/node = 8 record-slots x 4 feature-lanes (float4 = 8 halves each);
// one record's 64B row fetched by 4 lanes in a single dwordx4 each; window=64
// records -> the record loop runs once for virtually all nodes (Poisson deg~16),
// up to 8 predicated 16B gathers in flight per lane.
__global__ __launch_bounds__(256, 6)
void pull_kernel(const int* __restrict__ recs, const int* __restrict__ row_start,
                 const __half* __restrict__ h, const float* __restrict__ dis,
                 const float* __restrict__ bias, float* __restrict__ out,
                 int n, int relu_out) {
    int t = threadIdx.x;
    int node = blockIdx.x * 8 + (t >> 5);
    if (node >= n) return;
    int l32 = t & 31;
    int sub = l32 >> 2;   // record slot 0..7
    int fb = l32 & 3;     // float4 feature block (8 halves)
    int start = row_start[node];
    int deg = row_start[node + 1] - start;
    const float4* h4 = (const float4*)h;  // 8 halves per float4, 4 per row
    float s0 = 0, s1 = 0, s2 = 0, s3 = 0, s4 = 0, s5 = 0, s6 = 0, s7 = 0;
    for (int r0 = 0; r0 < deg; r0 += 64) {
#pragma unroll
        for (int w = 0; w < 8; ++w) {
            int r = r0 + w * 8 + sub;
            if (r < deg) {
                int s = recs[start + r];
                float4 v = h4[(size_t)s * 4 + fb];
                const __half2* hp = (const __half2*)&v;
                float2 a = __half22float2(hp[0]);
                float2 b = __half22float2(hp[1]);
                float2 c = __half22float2(hp[2]);
                float2 d = __half22float2(hp[3]);
                s0 += a.x; s1 += a.y; s2 += b.x; s3 += b.y;
                s4 += c.x; s5 += c.y; s6 += d.x; s7 += d.y;
            }
        }
    }
    // reduce across the 8 record slots (xor 4,8,16 stays within the 32-group)
#pragma unroll
    for (int m = 4; m <= 16; m <<= 1) {
        s0 += __shfl_xor(s0, m, 64); s1 += __shfl_xor(s1, m, 64);
        s2 += __shfl_xor(s2, m, 64); s3 += __shfl_xor(s3, m, 64);
        s4 += __shfl_xor(s4, m, 64); s5 += __shfl_xor(s5, m, 64);
        s6 += __shfl_xor(s6, m, 64); s7 += __shfl_xor(s7, m, 64);
    }
    if (sub == 0) {
        float dn = dis[node];
        float4 hv = h4[(size_t)node * 4 + fb];   // self-loop: + h~[node]
        const __half2* hp = (const __half2*)&hv;
        float2 a = __half22float2(hp[0]);
        float2 b = __half22float2(hp[1]);
        float2 c = __half22float2(hp[2]);
        float2 d = __half22float2(hp[3]);
        const float4* bv4 = (const float4*)bias;
        float4 b0 = bv4[fb * 2], b1 = bv4[fb * 2 + 1];
        float4 o0, o1;
        o0.x = fmaf(dn, s0 + a.x, b0.x);
        o0.y = fmaf(dn, s1 + a.y, b0.y);
        o0.z = fmaf(dn, s2 + b.x, b0.z);
        o0.w = fmaf(dn, s3 + b.y, b0.w);
        o1.x = fmaf(dn, s4 + c.x, b1.x);
        o1.y = fmaf(dn, s5 + c.y, b1.y);
        o1.z = fmaf(dn, s6 + d.x, b1.z);
        o1.w = fmaf(dn, s7 + d.y, b1.w);
        if (relu_out) {
            o0.x = fmaxf(o0.x, 0.0f); o0.y = fmaxf(o0.y, 0.0f);
            o0.z = fmaxf(o0.z, 0.0f); o0.w = fmaxf(o0.w, 0.0f);
            o1.x = fmaxf(o1.x, 0.0f); o1.y = fmaxf(o1.y, 0.0f);
            o1.z = fmaxf(o1.z, 0.0f); o1.w = fmaxf(o1.w, 0.0f);
        }
        ((float4*)out)[(size_t)node * 8 + fb * 2] = o0;
        ((float4*)out)[(size_t)node * 8 + fb * 2 + 1] = o1;
    }
}

extern "C" void kernel_launch(void* const* d_in, const int* in_sizes, int n_in,
                              void* d_out, int out_size, void* d_ws, size_t ws_size,
                              hipStream_t stream) {
    const float* x = (const float*)d_in[0];
    const void* eidx_raw = d_in[1];
    const float* W1 = (const float*)d_in[2];
    const float* b1 = (const float*)d_in[3];
    const float* W2 = (const float*)d_in[4];
    const float* b2 = (const float*)d_in[5];
    float* out = (float*)d_out;

    const int n = in_sizes[0] / FEAT;                    // 100000
    const int e = in_sizes[1] / 2;                       // 1600000
    const int nb = (n + BIN_NODES - 1) / BIN_NODES;      // 782
    const int nblk = (e + TILE_EDGES - 1) / TILE_EDGES;  // 196
    const int M = nb * nblk;                             // 153k
    const int nbks = (M + 255) / 256;                    // 599 <= 1024

    // Workspace (256B-aligned). `packed` aliases `acc1` (packed dead after
    // degsort, acc1 first written by pull1).
    char* ws = (char*)d_ws;
    size_t off = 0;
    auto alloc = [&](size_t bytes) { char* p = ws + off; off = (off + bytes + 255) & ~(size_t)255; return p; };
    int*    mat       = (int*)   alloc((size_t)M * 4);
    int*    bsum      = (int*)   alloc((size_t)nbks * 4);
    float*  dis       = (float*) alloc((size_t)n * 4);
    int*    row_start = (int*)   alloc((size_t)(n + 1) * 4);
    int*    recs      = (int*)   alloc((size_t)e * 4);
    __half* h         = (__half*)alloc((size_t)n * FEAT * 2);
    float*  acc1      = (float*) alloc((size_t)n * FEAT * 4);
    int*    packed    = (int*)acc1;   // e*4 = 6.4MB <= 12.8MB

    const size_t ldsA = (size_t)(BWAVES * nb + 1) * 4;   // ~50 KB
    const size_t ldsC = (size_t)(nb + 1) * 4;            // ~3.1 KB
    const int gNode = (n + 7) / 8;

    // CSR build (round-10 proven)
    binA_kernel<<<nblk, 1024, ldsA, stream>>>(eidx_raw, mat, e, nb);
    scan1_kernel<<<nbks, 256, 0, stream>>>(mat, bsum, M, nb, nblk);
    scan2_kernel<<<1, 1024, 0, stream>>>(bsum, nbks);
    binC_kernel<<<nblk, 1024, ldsC, stream>>>(eidx_raw, mat, bsum, packed, e, nb, nblk);
    degsort_kernel<<<nb, 1024, 0, stream>>>(packed, mat, bsum, dis, row_start,
                                            recs, e, n, nb, nblk);

    // Layer 1
    matmul_kernel<<<gNode, 256, 0, stream>>>(x, W1, dis, h, n, 0);
    pull_kernel<<<gNode, 256, 0, stream>>>(recs, row_start, h, dis, b1, acc1, n, 0);

    // Layer 2 (relu on read of acc1; final relu fused in writeout)
    matmul_kernel<<<gNode, 256, 0, stream>>>(acc1, W2, dis, h, n, 1);
    pull_kernel<<<gNode, 256, 0, stream>>>(recs, row_start, h, dis, b2, out, n, 1);
}